// Round 12
// baseline (274.604 us; speedup 1.0000x reference)
//
#include <hip/hip_runtime.h>
#include <cstdint>
#include <cstddef>

// Problem constants (fixed by reference)
#define NR   268
#define NB   256
#define NN   (NR*NB)        // 68608 nodes
#define IC   256
#define OC   64
#define DEG  32
#define EPG  (NR*DEG)       // 8576 edges per graph
#define NE   (NN*DEG)       // 2195456 edges
#define KK   214            // top-k per graph

// d_out layout (floats, concatenated outputs)
#define XP_OFF 0            // x_pooled  (256*214, 64)
#define BP_OFF 3506176      // batch_pooled (256*214)
#define SC_OFF 3560960      // scores (68608)
#define PM_OFF 3629568      // perm (256*214)

// workspace layout (float offsets)
#define WS_XT   4390912     // 68608*64
#define WS_META 8781824     // 256 * PPG * 4 floats (edge-pair records)
#define WS_ROWS 13369344    // 256*(268+1) uint32 pair-row starts

#define PPG   4480          // pair capacity/graph: max Sum ceil(deg/2) = 4422
#define ZROW  (NR*OC)       // zero-row index in xts (for pair padding)

typedef float v2f __attribute__((ext_vector_type(2)));

// packed fp32 fma: d = a*b + c on both halves (VOP3P, VGPR-pair operands ONLY
// — SGPR sources are illegal for v_pk_fma_f32 on CDNA, the round-1 lesson)
__device__ __forceinline__ v2f pkfma(v2f a, v2f b, v2f c) {
    v2f d;
    asm("v_pk_fma_f32 %0, %1, %2, %3" : "=v"(d) : "v"(a), "v"(b), "v"(c));
    return d;
}

// ---------------------------------------------------------------------------
// K_FRONT: csr role (256 blocks) + xtf role (536 blocks) interleaved mod-3
// (round-9 proven, absmax 0.0078125). Round-11 change: xtf K-tiles are
// register-PREFETCHED (xa/xb + 7 basis float4 in named regs, loaded for tile
// kt+32 right after the store barrier) so the 512-fma compute hides the
// global-load latency — k_front measured latency-bound (occ 28.6%, VALU 23%).
// csr role byte-identical to round 9 (same thread mapping -> same sum order).
// ---------------------------------------------------------------------------
#define NREP2 8
#define GS3 130
#define FRONT_LDS 64512
__global__ __launch_bounds__(512, 4) void k_front(const float* __restrict__ rc,
                                                  const float* __restrict__ basis,
                                                  const float* __restrict__ x,
                                                  float* __restrict__ xt,
                                                  const int* __restrict__ ei,
                                                  const float* __restrict__ ea,
                                                  float* __restrict__ meta,
                                                  unsigned int* __restrict__ rows) {
    extern __shared__ __align__(16) unsigned char dynsm[];
    int bid = blockIdx.x;
    int tid = threadIdx.x;
    bool csr_role = (bid < 768) && (bid % 3 == 1);

    if (csr_role) {
        // ---- csr: per-graph counting sort by dst, paired LDS records ----
        int g = bid / 3;
        unsigned int* cnt = (unsigned int*)dynsm;           // [NREP2][NR]
        unsigned int* tot = cnt + NREP2*NR;                 // [NR]
        unsigned int* prs = tot + NR;                       // [NR]
        unsigned int* pkb = prs + NR;                       // [PPG]
        float* daA = (float*)(pkb + PPG);                   // [PPG]
        float* daB = daA + PPG;                             // [PPG]
        int wid = tid >> 6;                                 // 0..7, 1/wave
        for (int i = tid; i < NREP2*NR; i += 512) cnt[i] = 0u;
        for (int i = tid; i < PPG; i += 512) pkb[i] = 0u;
        __syncthreads();
        int ebase = g * EPG;
        for (int e = tid; e < EPG; e += 512) {
            int ld = ei[NE + ebase + e] - g * NR;
            atomicAdd(&cnt[wid*NR + ld], 1u);
        }
        __syncthreads();
        for (int r = tid; r < NR; r += 512) {
            unsigned t = 0;
#pragma unroll
            for (int s = 0; s < NREP2; ++s) t += cnt[s*NR + r];
            tot[r] = t;
        }
        __syncthreads();
        if (tid < 64) {                      // wave 0: excl scan of pair counts
            unsigned run = 0;
            for (int base = 0; base < NR; base += 64) {
                int idx = base + tid;
                unsigned v = (idx < NR) ? ((tot[idx] + 1u) >> 1) : 0u;
                unsigned orig = v;
#pragma unroll
                for (int s = 1; s < 64; s <<= 1) {
                    int t = __shfl_up((int)v, (unsigned)s, 64);
                    if (tid >= s) v += (unsigned)t;
                }
                if (idx < NR) prs[idx] = run + v - orig;
                run += (unsigned)__shfl((int)v, 63, 64);
            }
        }
        __syncthreads();
        // in-place: cnt -> intra-row rank bases per replica
        for (int r = tid; r < NR; r += 512) {
            unsigned base = 0;
#pragma unroll
            for (int s = 0; s < NREP2; ++s) {
                unsigned t = cnt[s*NR + r]; cnt[s*NR + r] = base; base += t;
            }
        }
        __syncthreads();
        unsigned lastPairs = (tot[NR-1] + 1u) >> 1;
        for (int i = tid; i < NR + 1; i += 512)
            rows[(size_t)g * (NR + 1) + i] =
                (i < NR) ? prs[i] : (prs[NR-1] + lastPairs);
        // pass 2: emit into LDS (atomicOr composes the two u16 slots)
        for (int e = tid; e < EPG; e += 512) {
            int src = ei[ebase + e] - g * NR;
            int ld  = ei[NE + ebase + e] - g * NR;
            float a = ea[ebase + e];
            unsigned rank = atomicAdd(&cnt[wid*NR + ld], 1u);
            unsigned p = prs[ld] + (rank >> 1), sl = rank & 1u;
            atomicOr(&pkb[p], ((unsigned)src) << (16u * sl));
            if (sl) daB[p] = a - 0.5f; else daA[p] = a - 0.5f;
        }
        // pad odd rows: slot B of last pair -> zero-row, da = 0 (disjoint
        // addrs vs pass 2 for odd rows, safe concurrently)
        for (int r = tid; r < NR; r += 512) {
            if (tot[r] & 1u) {
                unsigned p = prs[r] + (tot[r] >> 1);
                atomicOr(&pkb[p], 268u << 16);
                daB[p] = 0.f;
            }
        }
        __syncthreads();
        // coalesced flush: 12 B LDS records -> 16 B float4 global records
        unsigned nPairs = prs[NR-1] + lastPairs;
        float4* __restrict__ mg = (float4*)(meta + (size_t)g * PPG * 4);
        for (unsigned i = tid; i < nPairs; i += 512) {
            unsigned pk = pkb[i];
            float4 f;
            f.x = __int_as_float((int)(pk & 0xFFFFu) * OC);
            f.y = __int_as_float((int)(pk >> 16) * OC);
            f.z = daA[i];
            f.w = daB[i];
            mg[i] = f;
        }
        return;
    }

    // ---- xtf role: xt[n] = x[n] @ roi_k[r], W tiles from basis, PREFETCHED --
    int idx = bid - ((bid < 768) ? (bid + 2) / 3 : 256);    // 0..535
    int r = idx % NR;
    int half = idx / NR;               // 0 or 1
    float* sXT = (float*)dynsm;                       // [32][GS3] 16.6 KB
    float* sW  = sXT + 32 * GS3;                      // [32][OC]   8 KB

    int lane = tid & 63;
    int wu = __builtin_amdgcn_readfirstlane(tid >> 6);   // wave id 0..7
    int g0 = lane * 2;                 // local graphs g0, g0+1
    int o0 = wu * 8;                   // channels o0..o0+7

    // softmax community weights for ROI r (wave-uniform s_loads)
    float cw[7];
    {
        float m = -1e30f;
#pragma unroll
        for (int j = 0; j < 7; ++j) { cw[j] = rc[r*7 + j]; m = fmaxf(m, cw[j]); }
        float s = 0.f;
#pragma unroll
        for (int j = 0; j < 7; ++j) { cw[j] = expf(cw[j] - m); s += cw[j]; }
        float inv = 1.f / s;
#pragma unroll
        for (int j = 0; j < 7; ++j) cw[j] *= inv;
    }

    // staging assignment: quad = c4/4 (0..7), grp = graph row (0..63), 2 reps
    int quad = tid & 7, grp = tid >> 3;
    const float* __restrict__ xrowA =
        x + ((size_t)(half*128 + grp) * NR + r) * IC + quad*4;
    const float* __restrict__ xrowB = xrowA + (size_t)64 * NR * IC;

    float acc[2][8];
#pragma unroll
    for (int i = 0; i < 2; ++i)
#pragma unroll
        for (int j = 0; j < 8; ++j) acc[i][j] = 0.f;

    // prologue: tile kt=0 loads into named regs
    float4 xa = *(const float4*)(xrowA);
    float4 xb = *(const float4*)(xrowB);
    float4 bv0, bv1, bv2, bv3, bv4, bv5, bv6;
    {
        int e0 = tid*4;
        bv0 = *(const float4*)(basis + (size_t)0*IC*OC + e0);
        bv1 = *(const float4*)(basis + (size_t)1*IC*OC + e0);
        bv2 = *(const float4*)(basis + (size_t)2*IC*OC + e0);
        bv3 = *(const float4*)(basis + (size_t)3*IC*OC + e0);
        bv4 = *(const float4*)(basis + (size_t)4*IC*OC + e0);
        bv5 = *(const float4*)(basis + (size_t)5*IC*OC + e0);
        bv6 = *(const float4*)(basis + (size_t)6*IC*OC + e0);
    }

    for (int kt = 0; kt < IC; kt += 32) {
        // build W elems from prefetched regs (same fma order as round 9)
        float4 w4 = make_float4(0.f, 0.f, 0.f, 0.f);
        #define WACC(J) { w4.x = fmaf(cw[J], bv##J.x, w4.x); \
                          w4.y = fmaf(cw[J], bv##J.y, w4.y); \
                          w4.z = fmaf(cw[J], bv##J.z, w4.z); \
                          w4.w = fmaf(cw[J], bv##J.w, w4.w); }
        WACC(0) WACC(1) WACC(2) WACC(3) WACC(4) WACC(5) WACC(6)
        #undef WACC
        __syncthreads();                 // prev compute done reading LDS
        sXT[(quad*4+0)*GS3 + grp] = xa.x;
        sXT[(quad*4+1)*GS3 + grp] = xa.y;
        sXT[(quad*4+2)*GS3 + grp] = xa.z;
        sXT[(quad*4+3)*GS3 + grp] = xa.w;
        sXT[(quad*4+0)*GS3 + 64 + grp] = xb.x;
        sXT[(quad*4+1)*GS3 + 64 + grp] = xb.y;
        sXT[(quad*4+2)*GS3 + 64 + grp] = xb.z;
        sXT[(quad*4+3)*GS3 + 64 + grp] = xb.w;
        *(float4*)(sW + tid*4) = w4;
        __syncthreads();
        // prefetch NEXT tile during the compute below (hides HBM/L2 latency)
        if (kt + 32 < IC) {
            xa = *(const float4*)(xrowA + kt + 32);
            xb = *(const float4*)(xrowB + kt + 32);
            int e0 = (kt + 32)*OC + tid*4;
            bv0 = *(const float4*)(basis + (size_t)0*IC*OC + e0);
            bv1 = *(const float4*)(basis + (size_t)1*IC*OC + e0);
            bv2 = *(const float4*)(basis + (size_t)2*IC*OC + e0);
            bv3 = *(const float4*)(basis + (size_t)3*IC*OC + e0);
            bv4 = *(const float4*)(basis + (size_t)4*IC*OC + e0);
            bv5 = *(const float4*)(basis + (size_t)5*IC*OC + e0);
            bv6 = *(const float4*)(basis + (size_t)6*IC*OC + e0);
        }

#pragma unroll 8
        for (int k = 0; k < 32; ++k) {
            float2 xv = *(const float2*)&sXT[k*GS3 + g0];
            float4 wa = *(const float4*)&sW[k*OC + o0];      // wave-uniform bcast
            float4 wb = *(const float4*)&sW[k*OC + o0 + 4];
            acc[0][0] = fmaf(xv.x, wa.x, acc[0][0]);
            acc[1][0] = fmaf(xv.y, wa.x, acc[1][0]);
            acc[0][1] = fmaf(xv.x, wa.y, acc[0][1]);
            acc[1][1] = fmaf(xv.y, wa.y, acc[1][1]);
            acc[0][2] = fmaf(xv.x, wa.z, acc[0][2]);
            acc[1][2] = fmaf(xv.y, wa.z, acc[1][2]);
            acc[0][3] = fmaf(xv.x, wa.w, acc[0][3]);
            acc[1][3] = fmaf(xv.y, wa.w, acc[1][3]);
            acc[0][4] = fmaf(xv.x, wb.x, acc[0][4]);
            acc[1][4] = fmaf(xv.y, wb.x, acc[1][4]);
            acc[0][5] = fmaf(xv.x, wb.y, acc[0][5]);
            acc[1][5] = fmaf(xv.y, wb.y, acc[1][5]);
            acc[0][6] = fmaf(xv.x, wb.z, acc[0][6]);
            acc[1][6] = fmaf(xv.y, wb.z, acc[1][6]);
            acc[0][7] = fmaf(xv.x, wb.w, acc[0][7]);
            acc[1][7] = fmaf(xv.y, wb.w, acc[1][7]);
        }
    }

#pragma unroll
    for (int i = 0; i < 2; ++i) {
        int g = half*128 + g0 + i;
        float* p = xt + ((size_t)g * NR + r) * OC + o0;
        float4 a; a.x = acc[i][0]; a.y = acc[i][1]; a.z = acc[i][2]; a.w = acc[i][3];
        float4 b; b.x = acc[i][4]; b.y = acc[i][5]; b.z = acc[i][6]; b.w = acc[i][7];
        *(float4*)p = a;
        *(float4*)(p + 4) = b;
    }
}

// ---------------------------------------------------------------------------
// K3 (fused tail) — round-9 form with ROW-PAIR INTERLEAVE: each wave gathers
// rows (r, r+16) together so the two rows' meta-load batches share latency
// windows and the serial LN/score chain of one row overlaps the other's
// loads. Per-row PAIR order unchanged (ascending j into that row's own acc)
// -> bitwise-identical sums vs round 9. h kept in LDS; rank-select top-K.
// ---------------------------------------------------------------------------
__global__ __launch_bounds__(1024, 4) void k_fused(
    const float* __restrict__ xt,
    const float4* __restrict__ meta,
    const unsigned int* __restrict__ rows,
    const float* __restrict__ ew_w, const float* __restrict__ ew_b,
    const float* __restrict__ conv_bias,
    const float* __restrict__ ln_g, const float* __restrict__ ln_b,
    const float* __restrict__ w1, const float* __restrict__ b1,
    const float* __restrict__ w2, const float* __restrict__ b2,
    float* __restrict__ out)
{
    extern __shared__ float smem[];          // xts (NR*OC+64) + h (NR*OC)
    float* xts = smem;
    float* hls = smem + (NR*OC + 64);
    __shared__ float rowbuf[16][OC];         // per-wave h row bounce, 4 KB
    __shared__ float scl[NR];
    __shared__ int ord[KK];                  // rank -> row

    int g = blockIdx.x;
    int tid = threadIdx.x;
    int o = tid & 63, w = tid >> 6;          // 16 waves

    // stage the graph's xt slice (coalesced float4) + zero pad row
    {
        const float4* s4 = (const float4*)(xt + (size_t)g * NR * OC);
        float4* d4 = (float4*)xts;
        for (int i = tid; i < NR*OC/4; i += 1024) d4[i] = s4[i];
        if (tid < 16) d4[NR*OC/4 + tid] = make_float4(0.f, 0.f, 0.f, 0.f);
    }

    float wo = ew_w[o], bo = ew_b[o], cb = conv_bias[o];
    float lng = ln_g[o], lnb = ln_b[o];
    float w2o = w2[o], b1o = b1[o], b2s = b2[0];
    float sgself = 1.f / (1.f + expf(-(wo + bo)));

    // degree-4 Taylor of sigmoid(wo*a + bo) in da = a - 0.5 (da precomputed)
    float z0 = fmaf(0.5f, wo, bo);
    float sg0 = 1.f / (1.f + expf(-z0));
    float u  = sg0 * (1.f - sg0);
    float d2 = u * (1.f - 2.f*sg0);
    float d3 = u * (1.f - 6.f*u);
    float d4c = d2 * (1.f - 12.f*u);
    float k1 = u * wo;
    float k2 = d2 * wo*wo * 0.5f;
    float k3 = d3 * wo*wo*wo * (1.f/6.f);
    float k4 = d4c * wo*wo*wo*wo * (1.f/24.f);
    v2f kd4 = {k4, k4}, kd3 = {k3, k3}, kd2 = {k2, k2}, kd1 = {k1, k1};
    v2f sdv = {sg0, sg0};

    // W1 column o in 32 named v2f regs
    #define LOADW(j) \
        v2f wcA##j = { w1[(4*j+0)*OC+o], w1[(4*j+1)*OC+o] }; \
        v2f wcB##j = { w1[(4*j+2)*OC+o], w1[(4*j+3)*OC+o] };
    LOADW(0)  LOADW(1)  LOADW(2)  LOADW(3)
    LOADW(4)  LOADW(5)  LOADW(6)  LOADW(7)
    LOADW(8)  LOADW(9)  LOADW(10) LOADW(11)
    LOADW(12) LOADW(13) LOADW(14) LOADW(15)
    #undef LOADW

    const float4* __restrict__ gm = meta + (size_t)g * PPG;
    const unsigned int* __restrict__ gr = rows + (size_t)g * (NR + 1);
    const float* __restrict__ xo = xts + o;
    __syncthreads();

    // pair body: 2 edges = 2 ds_read + 4 pk (Horner gate) + 1 pk (accumulate)
    #define PAIR(mp, acc) { \
        v2f xv; \
        xv.x = xo[__float_as_int((mp).x)]; \
        xv.y = xo[__float_as_int((mp).y)]; \
        v2f dv = { (mp).z, (mp).w }; \
        v2f t = pkfma(kd4, dv, kd3); \
        t = pkfma(t, dv, kd2); \
        t = pkfma(t, dv, kd1); \
        t = pkfma(t, dv, sdv); \
        acc = pkfma(xv, t, acc); }

    // ELU + LayerNorm + score for one finished row accumulator
    auto finish = [&](int r, v2f acc) {
        float accs = acc.x + acc.y + cb;
        float v = accs > 0.f ? accs : expm1f(accs);   // ELU (alpha=1)
        float s1 = v;
#pragma unroll
        for (int m = 1; m < 64; m <<= 1) s1 += __shfl_xor(s1, m, 64);
        float mu = s1 * (1.f/64.f);
        float d = v - mu;
        float s2 = d * d;
#pragma unroll
        for (int m = 1; m < 64; m <<= 1) s2 += __shfl_xor(s2, m, 64);
        float rsd = rsqrtf(s2 * (1.f/64.f) + 1e-5f);
        float h = fmaf(d * rsd, lng, lnb);
        hls[r*OC + o] = h;                   // kept in LDS for pool phase
        rowbuf[w][o] = h;
        const float* hr = rowbuf[w];
        v2f tA = { b1o, 0.f }, tB = { 0.f, 0.f };
        #define STEP(j) { float4 h4 = *(const float4*)(hr + 4*j); \
            v2f hl = { h4.x, h4.y }, hh = { h4.z, h4.w }; \
            tA = pkfma(hl, wcA##j, tA); tB = pkfma(hh, wcB##j, tB); }
        STEP(0)  STEP(1)  STEP(2)  STEP(3)
        STEP(4)  STEP(5)  STEP(6)  STEP(7)
        STEP(8)  STEP(9)  STEP(10) STEP(11)
        STEP(12) STEP(13) STEP(14) STEP(15)
        #undef STEP
        float t = (tA.x + tA.y) + (tB.x + tB.y);
        float a2 = fminf(fmaxf(2.f * t, -80.f), 80.f);
        float y = expf(a2);
        float th = (y - 1.f) / (y + 1.f);
        float p = th * w2o;
#pragma unroll
        for (int m = 1; m < 64; m <<= 1) p += __shfl_xor(p, m, 64);
        if (o == 0) {
            float sc = p + b2s;
            scl[r] = sc;
            out[SC_OFF + (size_t)g * NR + r] = sc;
        }
    };

    for (int i0 = 0; i0 < NR; i0 += 32) {
        int r1 = i0 + w;                     // wave-uniform
        if (r1 >= NR) continue;
        int r2 = r1 + 16;
        bool has2 = (r2 < NR);
        unsigned js1 = __builtin_amdgcn_readfirstlane(gr[r1]);
        unsigned je1 = __builtin_amdgcn_readfirstlane(gr[r1 + 1]);
        unsigned j2 = 0, je2 = 0;
        v2f acc1; acc1.x = xts[r1*OC + o] * sgself; acc1.y = 0.f;
        v2f acc2; acc2.x = 0.f; acc2.y = 0.f;
        if (has2) {
            j2  = __builtin_amdgcn_readfirstlane(gr[r2]);
            je2 = __builtin_amdgcn_readfirstlane(gr[r2 + 1]);
            acc2.x = xts[r2*OC + o] * sgself;
        }
        unsigned j1 = js1;
        // interleaved 4+4 batches: 8 independent loads per window, two accs
        while (j1 + 4 <= je1 && j2 + 4 <= je2) {
            float4 a0 = gm[j1], a1 = gm[j1+1], a2 = gm[j1+2], a3 = gm[j1+3];
            float4 b0 = gm[j2], b1 = gm[j2+1], b2 = gm[j2+2], b3 = gm[j2+3];
            PAIR(a0, acc1) PAIR(a1, acc1) PAIR(a2, acc1) PAIR(a3, acc1)
            PAIR(b0, acc2) PAIR(b1, acc2) PAIR(b2, acc2) PAIR(b3, acc2)
            j1 += 4; j2 += 4;
        }
        // row1 tail
        for (; j1 + 4 <= je1; j1 += 4) {
            float4 a0 = gm[j1], a1 = gm[j1+1], a2 = gm[j1+2], a3 = gm[j1+3];
            PAIR(a0, acc1) PAIR(a1, acc1) PAIR(a2, acc1) PAIR(a3, acc1)
        }
        for (; j1 < je1; ++j1) { float4 a0 = gm[j1]; PAIR(a0, acc1) }
        // row2 tail
        for (; j2 + 4 <= je2; j2 += 4) {
            float4 b0 = gm[j2], b1 = gm[j2+1], b2 = gm[j2+2], b3 = gm[j2+3];
            PAIR(b0, acc2) PAIR(b1, acc2) PAIR(b2, acc2) PAIR(b3, acc2)
        }
        for (; j2 < je2; ++j2) { float4 b0 = gm[j2]; PAIR(b0, acc2) }
        finish(r1, acc1);
        if (has2) finish(r2, acc2);
    }
    #undef PAIR
    __syncthreads();

    // rank-select top-K: rank(r) = #{s_j > s_r} + #{s_j == s_r, j < r}
    // — exactly the stable descending-sort position jax.lax.top_k uses.
    if (tid < NR) {
        float sr = scl[tid];
        int rank = 0;
        for (int jj = 0; jj < NR; ++jj) {
            float sj = scl[jj];
            rank += (sj > sr) || (sj == sr && jj < tid);
        }
        if (rank < KK) ord[rank] = tid;
    }
    __syncthreads();

    // pooled outputs (h rows read straight from LDS)
    for (int k = w; k < KK; k += 16) {
        int r = ord[k];
        float v = scl[r];
        float gate = 1.f / (1.f + expf(-v));
        float hvv = hls[r*OC + o];
        out[XP_OFF + ((size_t)g*KK + k)*64 + o] = hvv * gate;
        if (o == 0) {
            out[BP_OFF + (size_t)g*KK + k] = (float)g;
            out[PM_OFF + (size_t)g*KK + k] = (float)(g*NR + r);
        }
    }
}

// ---------------------------------------------------------------------------
extern "C" void kernel_launch(void* const* d_in, const int* in_sizes, int n_in,
                              void* d_out, int out_size, void* d_ws, size_t ws_size,
                              hipStream_t stream) {
    const float* x     = (const float*)d_in[0];
    const int*   ei    = (const int*)d_in[1];
    const float* ea    = (const float*)d_in[2];
    // d_in[3] batch: structurally known (g = n / NR), unused
    const float* basis = (const float*)d_in[4];
    const float* rc    = (const float*)d_in[5];
    const float* ew_w  = (const float*)d_in[6];
    const float* ew_b  = (const float*)d_in[7];
    const float* cbias = (const float*)d_in[8];
    const float* ln_g  = (const float*)d_in[9];
    const float* ln_b  = (const float*)d_in[10];
    const float* w1    = (const float*)d_in[11];
    const float* b1    = (const float*)d_in[12];
    const float* w2    = (const float*)d_in[13];
    const float* b2    = (const float*)d_in[14];
    float* out = (float*)d_out;

    float* wsf = (float*)d_ws;
    float* xtb  = wsf + WS_XT;
    float* metaF = wsf + WS_META;
    unsigned int* rows = (unsigned int*)(wsf + WS_ROWS);

    size_t fused_lds = (size_t)(NR*OC + 64 + NR*OC) * sizeof(float); // 137472

    k_front<<<dim3(792), dim3(512), FRONT_LDS, stream>>>(rc, basis, x, xtb,
                                                         ei, ea, metaF, rows);
    k_fused<<<dim3(NB),  dim3(1024), fused_lds, stream>>>(
                                                  xtb, (const float4*)metaF, rows,
                                                  ew_w, ew_b, cbias, ln_g, ln_b,
                                                  w1, b1, w2, b2, out);
}